// Round 4
// baseline (947.345 us; speedup 1.0000x reference)
//
#include <hip/hip_runtime.h>
#include <math.h>

// Persistent cooperative kernel v4:
//  - 256 WGs x 512 thr (all 256 CUs, 8 waves/CU -> huge VGPR/occupancy margin,
//    coop-launch validation cannot reject the grid)
//  - 2 gate rows per wave held in persistent VGPRs; next-stage weights
//    prefetched into registers before each grid barrier
//  - custom flag-array grid barrier (agent scope, release/acquire, monotone
//    epochs) with a bounded spin: any protocol failure ends the kernel in
//    <0.3 s with wrong results (diagnosable) instead of hanging the container
//  - 29 grid syncs; identical FMA grouping/reduction order as the passing
//    500us/568us versions -> same numerics.

#define NB 256
#define NT 512
#define NWAVE 2048
#define SPIN_CAP (1 << 16)

__device__ __forceinline__ float sigf(float x) { return 1.0f / (1.0f + expf(-x)); }

__device__ __forceinline__ float wave_red(float v) {
#pragma unroll
    for (int s = 32; s; s >>= 1) v += __shfl_down(v, s, 64);
    return v;
}

// order-preserving float->uint encoding for atomicMax (inputs have no NaNs)
__device__ __forceinline__ unsigned encf(float f) {
    unsigned u = __float_as_uint(f);
    return (u & 0x80000000u) ? ~u : (u | 0x80000000u);
}
__device__ __forceinline__ float decf(unsigned e) {
    return (e & 0x80000000u) ? __uint_as_float(e ^ 0x80000000u) : __uint_as_float(~e);
}

__device__ __forceinline__ float dotf(const float* __restrict__ w,
                                      const float* __restrict__ x, int lane) {
    float acc = 0.f;
#pragma unroll
    for (int j = 0; j < 4; ++j) {
        float4 a = *reinterpret_cast<const float4*>(w + j * 256 + lane * 4);
        float4 b = *reinterpret_cast<const float4*>(x + j * 256 + lane * 4);
        acc += a.x * b.x + a.y * b.y + a.z * b.z + a.w * b.w;
    }
    return acc;
}

// load one 1024-float row into 16 registers (lane-strided float4 layout)
__device__ __forceinline__ void ldrow(const float* __restrict__ src, int lane, float* r) {
    const float4* s4 = reinterpret_cast<const float4*>(src);
#pragma unroll
    for (int k = 0; k < 4; ++k) {
        float4 a = s4[k * 64 + lane];
        r[4 * k] = a.x; r[4 * k + 1] = a.y; r[4 * k + 2] = a.z; r[4 * k + 3] = a.w;
    }
}

// dot of register row with global x (same FMA grouping as dotf)
__device__ __forceinline__ float dotr(const float* r, const float* __restrict__ x, int lane) {
    float acc = 0.f;
    const float4* x4 = reinterpret_cast<const float4*>(x);
#pragma unroll
    for (int k = 0; k < 4; ++k) {
        float4 xv = x4[k * 64 + lane];
        acc += r[4 * k] * xv.x + r[4 * k + 1] * xv.y +
               r[4 * k + 2] * xv.z + r[4 * k + 3] * xv.w;
    }
    return acc;
}

// Grid barrier. bar[0] = generation; bar[64+b] = per-WG epoch flag.
// Arrive: WG b's tid0 release-stores its flag = ep. WG0's wave 0 scans all 256
// flags (4/lane), then tid0 release-stores generation = ep; all other WGs'
// tid0 acquire-poll the generation. Monotone epochs -> no reset race. Bounded
// spin converts any protocol failure into a fast wrong-answer, not a hang.
__device__ __forceinline__ void gsync(unsigned* bar, unsigned ep) {
    __syncthreads();
    if (blockIdx.x == 0) {
        if (threadIdx.x == 0)
            __hip_atomic_store(&bar[64], ep, __ATOMIC_RELEASE, __HIP_MEMORY_SCOPE_AGENT);
        if (threadIdx.x < 64) {
            int cnt = 0;
            for (;;) {
                unsigned mn = 0xffffffffu;
#pragma unroll
                for (int k = 0; k < 4; ++k) {
                    unsigned v = __hip_atomic_load(&bar[64 + threadIdx.x + 64 * k],
                                                   __ATOMIC_ACQUIRE, __HIP_MEMORY_SCOPE_AGENT);
                    if (v < mn) mn = v;
                }
                if (mn >= ep || ++cnt > SPIN_CAP) break;
                __builtin_amdgcn_s_sleep(4);
            }
            if (threadIdx.x == 0)
                __hip_atomic_store(&bar[0], ep, __ATOMIC_RELEASE, __HIP_MEMORY_SCOPE_AGENT);
        }
    } else {
        if (threadIdx.x == 0) {
            __hip_atomic_store(&bar[64 + blockIdx.x], ep, __ATOMIC_RELEASE,
                               __HIP_MEMORY_SCOPE_AGENT);
            int cnt = 0;
            while (__hip_atomic_load(&bar[0], __ATOMIC_ACQUIRE, __HIP_MEMORY_SCOPE_AGENT) < ep) {
                if (++cnt > SPIN_CAP) break;
                __builtin_amdgcn_s_sleep(4);
            }
        }
    }
    __syncthreads();
}

// zero barrier state + colmax accumulators (runs before mega_k every replay)
__global__ void init_k(unsigned* u) { u[blockIdx.x * 256 + threadIdx.x] = 0; }

__global__ void __launch_bounds__(NT, 2) mega_k(
    const float* __restrict__ tsn, const float* __restrict__ W_fe,
    const float* __restrict__ b_fe, const float* __restrict__ gW_ih0,
    const float* __restrict__ gW_ihR, const float* __restrict__ gb_ih,
    const float* __restrict__ gb_hh, const float* __restrict__ rW_ih,
    const float* __restrict__ rW_hh, const float* __restrict__ rb_ih,
    const float* __restrict__ rb_hh, const float* __restrict__ Wp,
    const float* __restrict__ bp, const float* __restrict__ We2a,
    const float* __restrict__ be2a, const float* __restrict__ We2v,
    const float* __restrict__ be2v, const float* __restrict__ We2n,
    const float* __restrict__ be2n, float* out, float* ws) {

    unsigned* bar = (unsigned*)ws;            // [0]=gen, [64..320)=flags
    unsigned* maxenc = (unsigned*)ws + 512;   // 1024 encoded col maxes
    float* fs   = ws + 2048;
    float* hgA  = ws + 3072;
    float* hgB  = ws + 4096;
    float* sv   = ws + 5120;                  // sv1 then sv2 (reused)
    float* ajs1 = ws + 8192;                  // 10*1024
    float* nfs1 = ws + 18432;
    float* ajs2 = ws + 28672;
    float* nfs2 = ws + 38912;                 // ends 49152 floats (192 KiB)

    __shared__ float sh_x[2048];   // [a2in | f2in]
    __shared__ float sh_pa[2048];  // pa[2][1024]
    __shared__ float gg[16];
    __shared__ float cc_l[4];
    __shared__ float sh_d[12];
    __shared__ float sh_s1[10];
    __shared__ float sh_bd1;
    __shared__ int   sh_istar;
    __shared__ int   sh_sel[2];

    const int tid = threadIdx.x, b = blockIdx.x;
    const int w = tid >> 6, lane = tid & 63;   // 8 waves/WG
    const int g4 = w >> 1, jr = w & 1;         // wave = (gate g4, row pair jr)
    const int jb = 4 * b;                      // this WG's h-slice base
    const int l0 = 2 * jr, l1 = l0 + 1;        // local j offsets (0..3)
    const int row0 = (g4 << 10) + jb + l0;     // global gate-matrix rows
    const int row1 = row0 + 1;
    const int rowG = jb + (w & 3);             // Wp row for nfs stages
    unsigned ep = 0;

    // ---- A: persistent weights -> regs; colmax(tsn); prefetch C + D0 ----
    float wr0[16], wr1[16], pw0[16], pw1[16], pwC[16], wf[16];
    {
        ldrow(rW_hh + (size_t)row0 * 1024, lane, wr0);
        ldrow(rW_hh + (size_t)row1 * 1024, lane, wr1);
        if (w < 4) ldrow(W_fe + (size_t)(jb + w) * 1024, lane, pwC);
        ldrow(gW_ih0 + (size_t)row0 * 2048, lane, pw0);  // D0 cols 0:1024
        ldrow(gW_ih0 + (size_t)row1 * 2048, lane, pw1);
        float m0 = -INFINITY, m1 = -INFINITY;
        const float* tb = tsn + (size_t)(16 * b) * 1024;
#pragma unroll 4
        for (int r = 0; r < 16; ++r) {
            m0 = fmaxf(m0, tb[(size_t)r * 1024 + tid]);
            m1 = fmaxf(m1, tb[(size_t)r * 1024 + tid + 512]);
        }
        atomicMax(&maxenc[tid], encf(m0));
        atomicMax(&maxenc[tid + 512], encf(m1));
    }
    gsync(bar, ++ep);

    // ---- C: fs = W_fe @ maxv + b_fe (4 rows/WG, weights prefetched) ----
    if (w < 4) {
        const uint4* e4 = reinterpret_cast<const uint4*>(maxenc);
        float acc = 0.f;
#pragma unroll
        for (int k = 0; k < 4; ++k) {
            uint4 e = e4[k * 64 + lane];
            acc += pwC[4 * k] * decf(e.x) + pwC[4 * k + 1] * decf(e.y) +
                   pwC[4 * k + 2] * decf(e.z) + pwC[4 * k + 3] * decf(e.w);
        }
        acc = wave_red(acc);
        if (lane == 0) fs[jb + w] = acc + b_fe[jb + w];
    }
    gsync(bar, ++ep);

    // ---- D: 5-layer goal LSTM (zero states), weights prefetched ----
    {
        const float* xin = fs;
        float* hout = hgA;
#pragma unroll 1
        for (int L = 0; L < 5; ++L) {
            float a0 = dotr(pw0, xin, lane);
            float a1 = dotr(pw1, xin, lane);
            a0 = wave_red(a0);
            a1 = wave_red(a1);
            if (lane == 0) {
                gg[g4 * 4 + l0] = a0 + gb_ih[L * 4096 + row0] + gb_hh[L * 4096 + row0];
                gg[g4 * 4 + l1] = a1 + gb_ih[L * 4096 + row1] + gb_hh[L * 4096 + row1];
            }
            // prefetch next layer (or stage-E weights: rW_ih cols 1024:2048)
            const float* n0 = (L < 4) ? (gW_ihR + (size_t)L * 4194304 + (size_t)row0 * 1024)
                                      : (rW_ih + (size_t)row0 * 2048 + 1024);
            const float* n1 = (L < 4) ? (gW_ihR + (size_t)L * 4194304 + (size_t)row1 * 1024)
                                      : (rW_ih + (size_t)row1 * 2048 + 1024);
            ldrow(n0, lane, pw0);
            ldrow(n1, lane, pw1);
            __syncthreads();
            if (tid < 4) {
                float gi = gg[tid], gc = gg[8 + tid], go = gg[12 + tid];
                float c = sigf(gi) * tanhf(gc);
                hout[jb + tid] = sigf(go) * tanhf(c);
            }
            gsync(bar, ++ep);
            xin = hout;
            hout = (hout == hgA) ? hgB : hgA;
        }
    }
    const float* gv = hgA;  // goal state g

    // ---- E: exp-1 fixed gates + cell0 + sv1 + cur_action; preload wf ----
    float gxr0 = 0.f, gxr1 = 0.f;  // fixed-input gate preacts (lane0-valid)
    {
        float a0 = dotr(pw0, fs, lane);
        float a1 = dotr(pw1, fs, lane);
        a0 = wave_red(a0);
        a1 = wave_red(a1);
        if (lane == 0) {
            gxr0 = a0 + rb_ih[row0] + rb_hh[row0];
            gxr1 = a1 + rb_ih[row1] + rb_hh[row1];
            gg[g4 * 4 + l0] = gxr0;
            gg[g4 * 4 + l1] = gxr1;
        }
        __syncthreads();
        if (tid < 4) {
            float gi = gg[tid], gc = gg[8 + tid], go = gg[12 + tid];
            float c = sigf(gi) * tanhf(gc);
            cc_l[tid] = c;
            ajs1[jb + tid] = sigf(go) * tanhf(c);
        }
        ldrow(Wp + (size_t)rowG * 3072 + 1024, lane, wf);
#pragma unroll 1
        for (int tt = w * 256 + b; tt < 3537; tt += 2048) {
            if (tt < 1024) {  // sv1 = Wp[:,0:1024]@fs + Wp[:,2048:]@g + bp
                float a2 = dotf(Wp + (size_t)tt * 3072, fs, lane) +
                           dotf(Wp + (size_t)tt * 3072 + 2048, gv, lane);
                a2 = wave_red(a2);
                if (lane == 0) sv[tt] = a2 + bp[tt];
            } else {          // cur_action
                int r = tt - 1024;
                float a2 = dotf(We2a + (size_t)r * 1024, fs, lane);
                a2 = wave_red(a2);
                if (lane == 0) out[11100 + r] = a2 + be2a[r];
            }
        }
    }
    gsync(bar, ++ep);

    // ---- F: exp-1 recurrence t=1..9 (weights in regs) ----
#pragma unroll 1
    for (int t = 1; t < 10; ++t) {
        const float* hp = ajs1 + (t - 1) * 1024;
        float a0 = dotr(wr0, hp, lane);
        float a1 = dotr(wr1, hp, lane);
        a0 = wave_red(a0);
        a1 = wave_red(a1);
        if (lane == 0) { gg[g4 * 4 + l0] = a0 + gxr0; gg[g4 * 4 + l1] = a1 + gxr1; }
        __syncthreads();
        if (tid < 4) {
            float gi = gg[tid], gf = gg[4 + tid], gc = gg[8 + tid], go = gg[12 + tid];
            float c = sigf(gi) * tanhf(gc) + sigf(gf) * cc_l[tid];
            cc_l[tid] = c;
            ajs1[t * 1024 + jb + tid] = sigf(go) * tanhf(c);
        }
        gsync(bar, ++ep);
    }

    // ---- G: nfs1 (wave = (rowG, 5 timesteps)); prefetch I weights ----
    {
        const int tp = w >> 2;  // 0 or 1
#pragma unroll 1
        for (int ii = 0; ii < 5; ++ii) {
            int t = tp + 2 * ii;
            float acc = dotr(wf, ajs1 + t * 1024, lane);
            acc = wave_red(acc);
            if (lane == 0) nfs1[t * 1024 + rowG] = fmaxf(sv[rowG] + acc, 0.f);
        }
        ldrow(rW_ih + (size_t)row0 * 2048, lane, pw0);  // I: cols 0:1024
        ldrow(rW_ih + (size_t)row1 * 2048, lane, pw1);
    }
    gsync(bar, ++ep);

    // ---- H+I: redundant scores1/argmin per WG, exp-2 gates + cell0 + sv2 ----
    {
#pragma unroll
        for (int pass = 0; pass < 2; ++pass) {
            int t = w + 8 * pass;
            if (t < 11) {
                const float* vv = (t < 10) ? (nfs1 + t * 1024) : fs;  // t==10 -> bd0
                const float4* v4 = reinterpret_cast<const float4*>(vv);
                const float4* q4 = reinterpret_cast<const float4*>(gv);
                float p = 0.f;
#pragma unroll
                for (int k = 0; k < 4; ++k) {
                    float4 v = v4[k * 64 + lane];
                    float4 gq = q4[k * 64 + lane];
                    float dx = v.x - gq.x, dy = v.y - gq.y, dz = v.z - gq.z, dw = v.w - gq.w;
                    p += dx * dx + dy * dy + dz * dz + dw * dw;
                }
                p = wave_red(p);
                if (lane == 0) sh_d[t] = p * (1.0f / 1024.0f);
            }
        }
        __syncthreads();
        if (tid == 0) {
            float bd = sh_d[10];
            float smin = INFINITY; int im = 0;
            for (int t = 0; t < 10; ++t) {
                float s = bd - sh_d[t];
                sh_s1[t] = s;
                if (s < smin) { smin = s; im = t; }
                if (sh_d[t] < bd) bd = sh_d[t];
            }
            sh_bd1 = bd; sh_istar = im;
        }
        __syncthreads();
        {
            int im = sh_istar;
#pragma unroll
            for (int j = tid; j < 1024; j += NT) {
                sh_x[j] = ajs1[im * 1024 + j];
                float f = nfs1[im * 1024 + j];
                sh_x[1024 + j] = f;
                if (b == 0) out[10076 + j] = f;
            }
        }
        __syncthreads();
        // I gates: rW_ih[:,0:1024]@a2in (regs) + rW_ih[:,1024:2048]@f2in (global)
        float a0 = 0.f, a1 = 0.f;
#pragma unroll
        for (int k = 0; k < 4; ++k) {
            float4 xv = *reinterpret_cast<const float4*>(&sh_x[k * 256 + lane * 4]);
            a0 += pw0[4 * k] * xv.x + pw0[4 * k + 1] * xv.y +
                  pw0[4 * k + 2] * xv.z + pw0[4 * k + 3] * xv.w;
            a1 += pw1[4 * k] * xv.x + pw1[4 * k + 1] * xv.y +
                  pw1[4 * k + 2] * xv.z + pw1[4 * k + 3] * xv.w;
        }
        const float* q0 = rW_ih + (size_t)row0 * 2048 + 1024;
        const float* q1 = rW_ih + (size_t)row1 * 2048 + 1024;
#pragma unroll
        for (int k = 0; k < 4; ++k) {
            float4 xv = *reinterpret_cast<const float4*>(&sh_x[1024 + k * 256 + lane * 4]);
            float4 u = *reinterpret_cast<const float4*>(q0 + k * 256 + lane * 4);
            float4 v = *reinterpret_cast<const float4*>(q1 + k * 256 + lane * 4);
            a0 += u.x * xv.x + u.y * xv.y + u.z * xv.z + u.w * xv.w;
            a1 += v.x * xv.x + v.y * xv.y + v.z * xv.z + v.w * xv.w;
        }
        a0 = wave_red(a0);
        a1 = wave_red(a1);
        if (lane == 0) {
            gxr0 = a0 + rb_ih[row0] + rb_hh[row0];
            gxr1 = a1 + rb_ih[row1] + rb_hh[row1];
            gg[g4 * 4 + l0] = gxr0;
            gg[g4 * 4 + l1] = gxr1;
        }
        __syncthreads();
        if (tid < 4) {
            float gi = gg[tid], gc = gg[8 + tid], go = gg[12 + tid];
            float c = sigf(gi) * tanhf(gc);
            cc_l[tid] = c;
            ajs2[jb + tid] = sigf(go) * tanhf(c);
        }
        if (w < 4) {  // sv2 = Wp[:,0:1024]@f2in + Wp[:,2048:]@g + bp
            int r = jb + w;
            const float* wp0 = Wp + (size_t)r * 3072;
            float a2 = 0.f;
#pragma unroll
            for (int k = 0; k < 4; ++k) {
                float4 a = *reinterpret_cast<const float4*>(wp0 + k * 256 + lane * 4);
                float4 xv = *reinterpret_cast<const float4*>(&sh_x[1024 + k * 256 + lane * 4]);
                a2 += a.x * xv.x + a.y * xv.y + a.z * xv.z + a.w * xv.w;
            }
            a2 += dotf(wp0 + 2048, gv, lane);
            a2 = wave_red(a2);
            if (lane == 0) sv[r] = a2 + bp[r];
        }
    }
    gsync(bar, ++ep);

    // ---- F': exp-2 recurrence t=1..9 ----
#pragma unroll 1
    for (int t = 1; t < 10; ++t) {
        const float* hp = ajs2 + (t - 1) * 1024;
        float a0 = dotr(wr0, hp, lane);
        float a1 = dotr(wr1, hp, lane);
        a0 = wave_red(a0);
        a1 = wave_red(a1);
        if (lane == 0) { gg[g4 * 4 + l0] = a0 + gxr0; gg[g4 * 4 + l1] = a1 + gxr1; }
        __syncthreads();
        if (tid < 4) {
            float gi = gg[tid], gf = gg[4 + tid], gc = gg[8 + tid], go = gg[12 + tid];
            float c = sigf(gi) * tanhf(gc) + sigf(gf) * cc_l[tid];
            cc_l[tid] = c;
            ajs2[t * 1024 + jb + tid] = sigf(go) * tanhf(c);
        }
        gsync(bar, ++ep);
    }

    // ---- J: nfs2 ----
    {
        const int tp = w >> 2;
#pragma unroll 1
        for (int ii = 0; ii < 5; ++ii) {
            int t = tp + 2 * ii;
            float acc = dotr(wf, ajs2 + t * 1024, lane);
            acc = wave_red(acc);
            if (lane == 0) nfs2[t * 1024 + rowG] = fmaxf(sv[rowG] + acc, 0.f);
        }
    }
    gsync(bar, ++ep);

    // ---- K+L: redundant scores2/top-2 per WG, pa in LDS, heads ----
    {
#pragma unroll
        for (int pass = 0; pass < 2; ++pass) {
            int t = w + 8 * pass;
            if (t < 10) {
                const float4* v4 = reinterpret_cast<const float4*>(nfs2 + t * 1024);
                const float4* q4 = reinterpret_cast<const float4*>(gv);
                float p = 0.f;
#pragma unroll
                for (int k = 0; k < 4; ++k) {
                    float4 v = v4[k * 64 + lane];
                    float4 gq = q4[k * 64 + lane];
                    float dx = v.x - gq.x, dy = v.y - gq.y, dz = v.z - gq.z, dw = v.w - gq.w;
                    p += dx * dx + dy * dy + dz * dz + dw * dw;
                }
                p = wave_red(p);
                if (lane == 0) sh_d[t] = p * (1.0f / 1024.0f);
            }
        }
        __syncthreads();
        if (tid == 0) {
            float sc[20];
            int im = sh_istar;
            for (int t = 0; t < 10; ++t) sc[t] = (t == im) ? INFINITY : sh_s1[t];
            float bd = sh_bd1;
            for (int t = 0; t < 10; ++t) {
                float s = bd - sh_d[t];
                sc[10 + t] = s;
                if (sh_d[t] < bd) bd = sh_d[t];
            }
            int i0 = 0; float m0 = INFINITY;
            for (int t = 0; t < 20; ++t) if (sc[t] < m0) { m0 = sc[t]; i0 = t; }
            int i1 = 0; float m1 = INFINITY;
            for (int t = 0; t < 20; ++t) { if (t == i0) continue; if (sc[t] < m1) { m1 = sc[t]; i1 = t; } }
            sh_sel[0] = i0; sh_sel[1] = i1;
        }
        __syncthreads();
#pragma unroll
        for (int p = 0; p < 2; ++p) {
            int idx = sh_sel[p];
#pragma unroll
            for (int j = tid; j < 1024; j += NT) {
                float av, fv;
                if (idx < 10) {
                    av = ajs1[idx * 1024 + j] * 0.5f;
                    fv = (fs[j] + nfs1[idx * 1024 + j]) * 0.5f;
                } else {
                    int t2 = idx - 10;
                    av = (sh_x[j] + ajs2[t2 * 1024 + j]) * (1.0f / 3.0f);
                    fv = (fs[j] + sh_x[1024 + j] + nfs2[t2 * 1024 + j]) * (1.0f / 3.0f);
                }
                sh_pa[p * 1024 + j] = av;
                if (b == 0) {
                    out[5980 + p * 1024 + j] = fv;      // pfeat
                    out[8028 + p * 1024 + j] = gv[j];   // pgoal
                }
            }
        }
        __syncthreads();
        // heads: 5980 dot-1024 tasks over 2048 waves, pa from LDS
#pragma unroll 1
        for (int t = w * 256 + b; t < 5980; t += 2048) {
            int p = (t < 2990) ? 0 : 1;
            int r = t - p * 2990;
            const float* W; const float* bb; int rr, outoff;
            if (r < 2513)      { W = We2a; bb = be2a; rr = r;        outoff = p * 2513 + rr; }
            else if (r < 2638) { W = We2v; bb = be2v; rr = r - 2513; outoff = 5026 + p * 125 + rr; }
            else               { W = We2n; bb = be2n; rr = r - 2638; outoff = 5276 + p * 352 + rr; }
            const float* wrow = W + (size_t)rr * 1024;
            float acc = 0.f;
#pragma unroll
            for (int k = 0; k < 4; ++k) {
                float4 a = *reinterpret_cast<const float4*>(wrow + k * 256 + lane * 4);
                float4 xv = *reinterpret_cast<const float4*>(&sh_pa[p * 1024 + k * 256 + lane * 4]);
                acc += a.x * xv.x + a.y * xv.y + a.z * xv.z + a.w * xv.w;
            }
            acc = wave_red(acc);
            if (lane == 0) out[outoff] = acc + bb[rr];
        }
    }
}

extern "C" void kernel_launch(void* const* d_in, const int* in_sizes, int n_in,
                              void* d_out, int out_size, void* d_ws, size_t ws_size,
                              hipStream_t stream) {
    const float* tsn    = (const float*)d_in[0];
    const float* W_fe   = (const float*)d_in[1];
    const float* b_fe   = (const float*)d_in[2];
    const float* gW_ih0 = (const float*)d_in[3];
    const float* gW_ihR = (const float*)d_in[4];
    // d_in[5] = gW_hh: multiplied by zero hidden state -> never needed
    const float* gb_ih  = (const float*)d_in[6];
    const float* gb_hh  = (const float*)d_in[7];
    const float* rW_ih  = (const float*)d_in[8];
    const float* rW_hh  = (const float*)d_in[9];
    const float* rb_ih  = (const float*)d_in[10];
    const float* rb_hh  = (const float*)d_in[11];
    const float* Wp     = (const float*)d_in[12];
    const float* bp     = (const float*)d_in[13];
    const float* We2a   = (const float*)d_in[14];
    const float* be2a   = (const float*)d_in[15];
    const float* We2v   = (const float*)d_in[16];
    const float* be2v   = (const float*)d_in[17];
    const float* We2n   = (const float*)d_in[18];
    const float* be2n   = (const float*)d_in[19];
    float* out = (float*)d_out;
    float* wsf = (float*)d_ws;

    init_k<<<8, 256, 0, stream>>>((unsigned*)d_ws);  // zero gen+flags+maxenc

    void* args[] = {
        (void*)&tsn,  (void*)&W_fe, (void*)&b_fe,  (void*)&gW_ih0, (void*)&gW_ihR,
        (void*)&gb_ih, (void*)&gb_hh, (void*)&rW_ih, (void*)&rW_hh, (void*)&rb_ih,
        (void*)&rb_hh, (void*)&Wp,   (void*)&bp,    (void*)&We2a,  (void*)&be2a,
        (void*)&We2v, (void*)&be2v,  (void*)&We2n,  (void*)&be2n,  (void*)&out,
        (void*)&wsf
    };
    hipLaunchCooperativeKernel((const void*)mega_k, dim3(NB), dim3(NT), args, 0, stream);
}

// Round 6
// 420.880 us; speedup vs baseline: 2.2509x; 2.2509x over previous
//
#include <hip/hip_runtime.h>
#include <math.h>

// Multi-kernel (graph-friendly) v6: round-0 structure, re-parallelized.
//  - kernel boundaries ARE the grid sync (few us in-graph; measured cheaper
//    than cg::sync ~16us or custom barriers ~22us on this harness)
//  - colmax: 256 blocks + order-preserving-encoded atomicMax (proven in v4)
//  - all GEMV/LSTM kernels: 512-thr 8-wave blocks, 256-block grids (round 0
//    ran 4-wave blocks = 1 wave/SIMD, latency-bound)
//  - cell0 fused into gate-GEMV epilogue; cur_action fused into heads
//  - identical per-dot FMA grouping/order as the 500us round-0 kernel

__device__ __forceinline__ float sigf(float x) { return 1.0f / (1.0f + expf(-x)); }

__device__ __forceinline__ float wave_red(float v) {
#pragma unroll
    for (int s = 32; s; s >>= 1) v += __shfl_down(v, s, 64);
    return v;
}

// order-preserving float->uint encoding for atomicMax (inputs have no NaNs)
__device__ __forceinline__ unsigned encf(float f) {
    unsigned u = __float_as_uint(f);
    return (u & 0x80000000u) ? ~u : (u | 0x80000000u);
}
__device__ __forceinline__ float decf(unsigned e) {
    return (e & 0x80000000u) ? __uint_as_float(e ^ 0x80000000u) : __uint_as_float(~e);
}

// dot of 1024 fp32 weights with 1024 fp32 x, one 64-lane wave
__device__ __forceinline__ float dotf(const float* __restrict__ w,
                                      const float* __restrict__ x, int lane) {
    float acc = 0.f;
#pragma unroll
    for (int j = 0; j < 4; ++j) {
        float4 a = *reinterpret_cast<const float4*>(w + j * 256 + lane * 4);
        float4 b = *reinterpret_cast<const float4*>(x + j * 256 + lane * 4);
        acc += a.x * b.x + a.y * b.y + a.z * b.z + a.w * b.w;
    }
    return acc;
}

// ---------------- init: zero encoded colmax accumulators ----------------
__global__ void init_k(unsigned* u) { u[blockIdx.x * 256 + threadIdx.x] = 0; }

// ---------------- colmax over tsn [4096,1024]: 256 blocks x 16 rows ------
__global__ void colmax_k(const float* __restrict__ tsn, unsigned* __restrict__ maxenc) {
    int tid = threadIdx.x;
    const float4* t4 = reinterpret_cast<const float4*>(tsn);
    float4 m = make_float4(-INFINITY, -INFINITY, -INFINITY, -INFINITY);
    int r0 = blockIdx.x * 16;
    for (int r = r0; r < r0 + 16; ++r) {
        float4 v = t4[(size_t)r * 256 + tid];
        m.x = fmaxf(m.x, v.x); m.y = fmaxf(m.y, v.y);
        m.z = fmaxf(m.z, v.z); m.w = fmaxf(m.w, v.w);
    }
    atomicMax(&maxenc[4 * tid + 0], encf(m.x));
    atomicMax(&maxenc[4 * tid + 1], encf(m.y));
    atomicMax(&maxenc[4 * tid + 2], encf(m.z));
    atomicMax(&maxenc[4 * tid + 3], encf(m.w));
}

// ---------------- fs = W_fe @ decode(maxenc) + b_fe ----------------
__global__ void fsdec_k(const float* __restrict__ W_fe, const unsigned* __restrict__ maxenc,
                        const float* __restrict__ b_fe, float* __restrict__ fs) {
    int w = threadIdx.x >> 6, lane = threadIdx.x & 63;
    int row = blockIdx.x * 4 + w;
    const float* wr = W_fe + (size_t)row * 1024;
    const uint4* e4 = reinterpret_cast<const uint4*>(maxenc);
    float acc = 0.f;
#pragma unroll
    for (int k = 0; k < 4; ++k) {
        float4 a = *reinterpret_cast<const float4*>(wr + k * 256 + lane * 4);
        uint4 e = e4[k * 64 + lane];
        acc += a.x * decf(e.x) + a.y * decf(e.y) + a.z * decf(e.z) + a.w * decf(e.w);
    }
    acc = wave_red(acc);
    if (lane == 0) fs[row] = acc + b_fe[row];
}

// ---------------- generic GEMV (sv stages): y[r] = segA + segB + b1 + b2 ----
__global__ void gemv_k(const float* __restrict__ W, int ld, int nrows,
                       const float* __restrict__ xA, int offA,
                       const float* __restrict__ xB, int offB,
                       const float* __restrict__ b1, const float* __restrict__ b2,
                       float* __restrict__ y) {
    int w = threadIdx.x >> 6, lane = threadIdx.x & 63;
    int row = blockIdx.x * 4 + w;
    if (row >= nrows) return;
    const float* wr = W + (size_t)row * ld;
    float acc = 0.f;
    if (xA) acc += dotf(wr + offA, xA, lane);
    if (xB) acc += dotf(wr + offB, xB, lane);
    acc = wave_red(acc);
    if (lane == 0) {
        if (b1) acc += b1[row];
        if (b2) acc += b2[row];
        y[row] = acc;
    }
}

// ---------------- fused gates-GEMV + LSTM cell, 8-wave blocks ----------------
// Block b: j in [4b,4b+4). Wave w: gate = w>>1, jp = (w&1)*2 -> 2 rows.
__global__ void lstm8_k(const float* __restrict__ W, int ld, int off,
                        const float* __restrict__ x,
                        const float* __restrict__ b1, const float* __restrict__ b2,
                        const float* __restrict__ gx,
                        const float* __restrict__ cc_in,
                        float* __restrict__ cc_out, float* __restrict__ h_out) {
    __shared__ float glds[4][4];
    int tid = threadIdx.x, w = tid >> 6, lane = tid & 63;
    int gate = w >> 1, jp = (w & 1) * 2, j0 = blockIdx.x * 4;
    int r0 = (gate << 10) + j0 + jp;
    const float* wr0 = W + (size_t)r0 * ld + off;
    const float* wr1 = wr0 + ld;
    float a0 = dotf(wr0, x, lane);
    float a1 = dotf(wr1, x, lane);
    a0 = wave_red(a0);
    a1 = wave_red(a1);
    if (lane == 0) {
        if (b1) { a0 += b1[r0]; a1 += b1[r0 + 1]; }
        if (b2) { a0 += b2[r0]; a1 += b2[r0 + 1]; }
        if (gx) { a0 += gx[r0]; a1 += gx[r0 + 1]; }
        glds[gate][jp] = a0;
        glds[gate][jp + 1] = a1;
    }
    __syncthreads();
    if (tid < 4) {
        int j = j0 + tid;
        float gi = glds[0][tid], gf = glds[1][tid], gg = glds[2][tid], go = glds[3][tid];
        float c = sigf(gi) * tanhf(gg);
        if (cc_in) c += sigf(gf) * cc_in[j];
        float h = sigf(go) * tanhf(c);
        if (cc_out) cc_out[j] = c;
        h_out[j] = h;
    }
}

// ------ fixed-input gates GEMV (writes gx) + fused zero-state cell0 ------
// Block b: j in [4b,4b+4); wave w: gate = w>>1, jp = (w&1)*2 -> 2 rows.
__global__ void gxcell_k(const float* __restrict__ W, int ld,
                         const float* __restrict__ xA, int offA,
                         const float* __restrict__ xB, int offB,
                         const float* __restrict__ b1, const float* __restrict__ b2,
                         float* __restrict__ gx, float* __restrict__ cc_out,
                         float* __restrict__ h_out) {
    __shared__ float glds[4][4];
    int tid = threadIdx.x, w = tid >> 6, lane = tid & 63;
    int gate = w >> 1, jp = (w & 1) * 2, j0 = blockIdx.x * 4;
    int r0 = (gate << 10) + j0 + jp;
    const float* wr0 = W + (size_t)r0 * ld;
    const float* wr1 = wr0 + ld;
    float a0 = 0.f, a1 = 0.f;
    if (xA) { a0 += dotf(wr0 + offA, xA, lane); a1 += dotf(wr1 + offA, xA, lane); }
    if (xB) { a0 += dotf(wr0 + offB, xB, lane); a1 += dotf(wr1 + offB, xB, lane); }
    a0 = wave_red(a0);
    a1 = wave_red(a1);
    if (lane == 0) {
        a0 += b1[r0]; a1 += b1[r0 + 1];
        a0 += b2[r0]; a1 += b2[r0 + 1];
        gx[r0] = a0;
        gx[r0 + 1] = a1;
        glds[gate][jp] = a0;
        glds[gate][jp + 1] = a1;
    }
    __syncthreads();
    if (tid < 4) {
        int j = j0 + tid;
        float gi = glds[0][tid], gg = glds[2][tid], go = glds[3][tid];
        float c = sigf(gi) * tanhf(gg);
        float h = sigf(go) * tanhf(c);
        cc_out[j] = c;
        h_out[j] = h;
    }
}

// ---- nfs: block b rows i in [4b,4b+4); wave = (i, half): 5 timesteps ----
__global__ void nfs8_k(const float* __restrict__ Wp, const float* __restrict__ ajs,
                       const float* __restrict__ sv, float* __restrict__ nfs) {
    int tid = threadIdx.x, w = tid >> 6, lane = tid & 63;
    int i = blockIdx.x * 4 + (w & 3);
    int tp = w >> 2;  // 0 or 1
    const float* wr = Wp + (size_t)i * 3072 + 1024;
    float wf[16];
#pragma unroll
    for (int k = 0; k < 4; ++k) {
        float4 a = *reinterpret_cast<const float4*>(wr + k * 256 + lane * 4);
        wf[4 * k] = a.x; wf[4 * k + 1] = a.y; wf[4 * k + 2] = a.z; wf[4 * k + 3] = a.w;
    }
#pragma unroll 1
    for (int ii = 0; ii < 5; ++ii) {
        int t = tp + 2 * ii;
        const float* av = ajs + t * 1024;
        float acc = 0.f;
#pragma unroll
        for (int k = 0; k < 4; ++k) {
            float4 v = *reinterpret_cast<const float4*>(av + k * 256 + lane * 4);
            acc += wf[4 * k] * v.x + wf[4 * k + 1] * v.y + wf[4 * k + 2] * v.z +
                   wf[4 * k + 3] * v.w;
        }
        acc = wave_red(acc);
        if (lane == 0) nfs[t * 1024 + i] = fmaxf(sv[i] + acc, 0.f);
    }
}

// ---- scores of expansion 1 + bd0 + argmin + a2in/f2in extraction ----
__global__ void scores1_k(const float* __restrict__ nfs1, const float* __restrict__ g,
                          const float* __restrict__ fs, const float* __restrict__ ajs1,
                          float* __restrict__ s1, float* __restrict__ bd1_out,
                          int* __restrict__ istar_out, float* __restrict__ a2in,
                          float* __restrict__ f2in, float* __restrict__ out_f2in) {
    __shared__ float red[256];
    __shared__ float d[11];
    __shared__ int istar_sh;
    int tid = threadIdx.x;
    for (int t = 0; t < 11; ++t) {
        const float* v = (t < 10) ? (nfs1 + t * 1024) : fs;
        float p = 0.f;
        for (int j = tid * 4; j < tid * 4 + 4; ++j) { float df = v[j] - g[j]; p += df * df; }
        red[tid] = p; __syncthreads();
        for (int s = 128; s; s >>= 1) { if (tid < s) red[tid] += red[tid + s]; __syncthreads(); }
        if (tid == 0) d[t] = red[0] * (1.0f / 1024.0f);
        __syncthreads();
    }
    if (tid == 0) {
        float bd = d[10];  // bd0
        float smin = INFINITY; int im = 0;
        for (int t = 0; t < 10; ++t) {
            float s = bd - d[t];
            s1[t] = s;
            if (s < smin) { smin = s; im = t; }
            if (d[t] < bd) bd = d[t];
        }
        *bd1_out = bd; *istar_out = im; istar_sh = im;
    }
    __syncthreads();
    int im = istar_sh;
    for (int j = tid; j < 1024; j += 256) {
        float a = ajs1[im * 1024 + j], f = nfs1[im * 1024 + j];
        a2in[j] = a; f2in[j] = f; out_f2in[j] = f;
    }
}

// ---- scores of expansion 2 + top-2 select + pa/pfeat/pgoal outputs ----
__global__ void scores2_k(const float* __restrict__ nfs2, const float* __restrict__ g,
                          const float* __restrict__ fs, const float* __restrict__ ajs1,
                          const float* __restrict__ nfs1, const float* __restrict__ ajs2,
                          const float* __restrict__ a2in, const float* __restrict__ f2in,
                          const float* __restrict__ s1, const float* __restrict__ bd1,
                          const int* __restrict__ istar, float* __restrict__ pa,
                          float* __restrict__ out) {
    __shared__ float red[256];
    __shared__ float d[10];
    __shared__ int sel[2];
    int tid = threadIdx.x;
    for (int t = 0; t < 10; ++t) {
        const float* v = nfs2 + t * 1024;
        float p = 0.f;
        for (int j = tid * 4; j < tid * 4 + 4; ++j) { float df = v[j] - g[j]; p += df * df; }
        red[tid] = p; __syncthreads();
        for (int s = 128; s; s >>= 1) { if (tid < s) red[tid] += red[tid + s]; __syncthreads(); }
        if (tid == 0) d[t] = red[0] * (1.0f / 1024.0f);
        __syncthreads();
    }
    if (tid == 0) {
        float sc[20];
        int im = *istar;
        for (int t = 0; t < 10; ++t) sc[t] = (t == im) ? INFINITY : s1[t];
        float bd = *bd1;
        for (int t = 0; t < 10; ++t) {
            float s = bd - d[t];
            sc[10 + t] = s;
            if (d[t] < bd) bd = d[t];
        }
        int i0 = 0; float m0 = INFINITY;
        for (int t = 0; t < 20; ++t) if (sc[t] < m0) { m0 = sc[t]; i0 = t; }
        int i1 = 0; float m1 = INFINITY;
        for (int t = 0; t < 20; ++t) { if (t == i0) continue; if (sc[t] < m1) { m1 = sc[t]; i1 = t; } }
        sel[0] = i0; sel[1] = i1;
    }
    __syncthreads();
    for (int p = 0; p < 2; ++p) {
        int idx = sel[p];
        for (int j = tid; j < 1024; j += 256) {
            float av, fv;
            if (idx < 10) {
                av = ajs1[idx * 1024 + j] * 0.5f;
                fv = (fs[j] + nfs1[idx * 1024 + j]) * 0.5f;
            } else {
                int t = idx - 10;
                av = (a2in[j] + ajs2[t * 1024 + j]) * (1.0f / 3.0f);
                fv = (fs[j] + f2in[j] + nfs2[t * 1024 + j]) * (1.0f / 3.0f);
            }
            pa[p * 1024 + j] = av;
            out[5980 + p * 1024 + j] = fv;   // pfeat
            out[8028 + p * 1024 + j] = g[j]; // pgoal
        }
    }
}

// ---- heads for the 2 selected rows + cur_action (fs), 8 waves/block ----
__global__ void heads_k(const float* __restrict__ We2a, const float* __restrict__ be2a,
                        const float* __restrict__ We2v, const float* __restrict__ be2v,
                        const float* __restrict__ We2n, const float* __restrict__ be2n,
                        const float* __restrict__ pa, const float* __restrict__ fs,
                        float* __restrict__ out) {
    int w = threadIdx.x >> 6, lane = threadIdx.x & 63;
    int task = blockIdx.x * 8 + w;
    if (task >= 8493) return;
    if (task < 5980) {
        int p = (task < 2990) ? 0 : 1;
        int r = task - p * 2990;
        const float* W; const float* b; int rr, outoff;
        if (r < 2513)      { W = We2a; b = be2a; rr = r;        outoff = p * 2513 + rr; }
        else if (r < 2638) { W = We2v; b = be2v; rr = r - 2513; outoff = 5026 + p * 125 + rr; }
        else               { W = We2n; b = be2n; rr = r - 2638; outoff = 5276 + p * 352 + rr; }
        float acc = dotf(W + (size_t)rr * 1024, pa + p * 1024, lane);
        acc = wave_red(acc);
        if (lane == 0) out[outoff] = acc + b[rr];
    } else {
        int r = task - 5980;  // cur_action row
        float acc = dotf(We2a + (size_t)r * 1024, fs, lane);
        acc = wave_red(acc);
        if (lane == 0) out[11100 + r] = acc + be2a[r];
    }
}

extern "C" void kernel_launch(void* const* d_in, const int* in_sizes, int n_in,
                              void* d_out, int out_size, void* d_ws, size_t ws_size,
                              hipStream_t stream) {
    const float* tsn    = (const float*)d_in[0];
    const float* W_fe   = (const float*)d_in[1];
    const float* b_fe   = (const float*)d_in[2];
    const float* gW_ih0 = (const float*)d_in[3];
    const float* gW_ihR = (const float*)d_in[4];
    // d_in[5] = gW_hh: multiplied by zero hidden state -> never needed
    const float* gb_ih  = (const float*)d_in[6];
    const float* gb_hh  = (const float*)d_in[7];
    const float* rW_ih  = (const float*)d_in[8];
    const float* rW_hh  = (const float*)d_in[9];
    const float* rb_ih  = (const float*)d_in[10];
    const float* rb_hh  = (const float*)d_in[11];
    const float* Wp     = (const float*)d_in[12];
    const float* bp     = (const float*)d_in[13];
    const float* We2a   = (const float*)d_in[14];
    const float* be2a   = (const float*)d_in[15];
    const float* We2v   = (const float*)d_in[16];
    const float* be2v   = (const float*)d_in[17];
    const float* We2n   = (const float*)d_in[18];
    const float* be2n   = (const float*)d_in[19];
    float* out = (float*)d_out;

    float* w = (float*)d_ws;
    unsigned* maxenc = (unsigned*)d_ws;   // 1024 uints
    float* fs    = w + 1024;
    float* hgA   = w + 2048;
    float* hgB   = w + 3072;
    float* gx    = w + 4096;   // 4096
    float* cc0   = w + 8192;
    float* cc1   = w + 9216;
    float* sv    = w + 10240;
    float* a2in  = w + 11264;
    float* f2in  = w + 12288;
    float* pa    = w + 13312;  // 2048
    float* ajs1  = w + 15360;  // 10240
    float* nfs1  = w + 25600;
    float* ajs2  = w + 35840;
    float* nfs2  = w + 46080;  // ..56320
    float* s1    = w + 56320;  // 10
    float* bd1   = w + 56332;
    int*   istar = (int*)(w + 56336);

    // 1) column max + fs
    init_k<<<4, 256, 0, stream>>>(maxenc);
    colmax_k<<<256, 256, 0, stream>>>(tsn, maxenc);
    fsdec_k<<<256, 256, 0, stream>>>(W_fe, maxenc, b_fe, fs);

    // 2) goal LSTM: 5 layers, zero states => gates = x @ Wih.T + (gb_ih+gb_hh)
    lstm8_k<<<256, 512, 0, stream>>>(gW_ih0, 2048, 0, fs, gb_ih, gb_hh,
                                     nullptr, nullptr, nullptr, hgA);
    lstm8_k<<<256, 512, 0, stream>>>(gW_ihR + (size_t)0 * 4194304, 1024, 0, hgA,
                                     gb_ih + 4096, gb_hh + 4096, nullptr, nullptr, nullptr, hgB);
    lstm8_k<<<256, 512, 0, stream>>>(gW_ihR + (size_t)1 * 4194304, 1024, 0, hgB,
                                     gb_ih + 8192, gb_hh + 8192, nullptr, nullptr, nullptr, hgA);
    lstm8_k<<<256, 512, 0, stream>>>(gW_ihR + (size_t)2 * 4194304, 1024, 0, hgA,
                                     gb_ih + 12288, gb_hh + 12288, nullptr, nullptr, nullptr, hgB);
    lstm8_k<<<256, 512, 0, stream>>>(gW_ihR + (size_t)3 * 4194304, 1024, 0, hgB,
                                     gb_ih + 16384, gb_hh + 16384, nullptr, nullptr, nullptr, hgA);
    float* g = hgA;

    // 3) expansion 1: xin = concat(0, fs) -> cols 1024:2048; fused cell0
    gxcell_k<<<256, 512, 0, stream>>>(rW_ih, 2048, nullptr, 0, fs, 1024,
                                      rb_ih, rb_hh, gx, cc0, ajs1);
    for (int t = 1; t < 10; ++t) {
        float* cin = ((t - 1) & 1) ? cc1 : cc0;
        float* cout = (t & 1) ? cc1 : cc0;
        lstm8_k<<<256, 512, 0, stream>>>(rW_hh, 1024, 0, ajs1 + (t - 1) * 1024,
                                         nullptr, nullptr, gx, cin, cout, ajs1 + t * 1024);
    }
    gemv_k<<<256, 256, 0, stream>>>(Wp, 3072, 1024, fs, 0, g, 2048, bp, nullptr, sv);
    nfs8_k<<<256, 512, 0, stream>>>(Wp, ajs1, sv, nfs1);
    scores1_k<<<1, 256, 0, stream>>>(nfs1, g, fs, ajs1, s1, bd1, istar, a2in, f2in, out + 10076);

    // 4) expansion 2: xin = concat(a2in, f2in); fused cell0
    gxcell_k<<<256, 512, 0, stream>>>(rW_ih, 2048, a2in, 0, f2in, 1024,
                                      rb_ih, rb_hh, gx, cc0, ajs2);
    for (int t = 1; t < 10; ++t) {
        float* cin = ((t - 1) & 1) ? cc1 : cc0;
        float* cout = (t & 1) ? cc1 : cc0;
        lstm8_k<<<256, 512, 0, stream>>>(rW_hh, 1024, 0, ajs2 + (t - 1) * 1024,
                                         nullptr, nullptr, gx, cin, cout, ajs2 + t * 1024);
    }
    gemv_k<<<256, 256, 0, stream>>>(Wp, 3072, 1024, f2in, 0, g, 2048, bp, nullptr, sv);
    nfs8_k<<<256, 512, 0, stream>>>(Wp, ajs2, sv, nfs2);
    scores2_k<<<1, 256, 0, stream>>>(nfs2, g, fs, ajs1, nfs1, ajs2, a2in, f2in,
                                     s1, bd1, istar, pa, out);

    // 5) heads + cur_action (8493 dot-1024 tasks)
    heads_k<<<1062, 512, 0, stream>>>(We2a, be2a, We2v, be2v, We2n, be2n, pa, fs, out);
}